// Round 4
// baseline (1439.910 us; speedup 1.0000x reference)
//
#include <hip/hip_runtime.h>
#include <float.h>
#include <stdint.h>

#define IN_DIM 1433
#define HID 16
#define OUTD 7

// gemm1 tile geometry: 64 rows x 128 k-cols, double-buffered (64 KB LDS)
#define BR 64
#define KC2 128
#define NT2 ((IN_DIM + KC2 - 1) / KC2)       // 12
#define KLAST2 (IN_DIM - (NT2 - 1) * KC2)    // 25

// ------- fused GEMM1 + dst-histogram ------------------------------------------
// xw1[N][16] = feat[N][1433] @ W1[1433][16]; then this block's edge chunk
// contributes to cnt[] (int atomics hidden under gemm memory stalls).
// 256 threads = 4 waves; wave w owns output dims [4w,4w+4) (W1 loads are
// wave-uniform -> s_load). Thread's row r = t&63. LDS x-tile is staged with
// async global_load_lds (linear dest) from an XOR-pre-swizzled global source:
// slot p of row r holds global col (p&~31)|((p&31)^(r&31)) -> read of col kk
// hits bank (kk^r)&31 => 2 lanes/bank (free).
__global__ __launch_bounds__(256, 2) void gemm1_hist_kernel(
    const float* __restrict__ feat, const float* __restrict__ W1,
    float* __restrict__ xw1, int N,
    const int* __restrict__ edst, int* __restrict__ cnt, int E, int EPB)
{
    __shared__ float xs[2][BR * KC2];   // 2 * 32 KB
    const int t = threadIdx.x;
    const int lane = t & 63;
    const int w = t >> 6;
    const int row0 = blockIdx.x * BR;
    const long maxElem = (long)N * IN_DIM - 1;

    const int r  = t & 63;
    const int rx = r & 31;
    const int wq = __builtin_amdgcn_readfirstlane(w);

    float acc[4] = {0.f, 0.f, 0.f, 0.f};

    // stage one 64x128 tile: per wave 32 async instrs of 256B (rows 16w..16w+15)
    auto stage = [&](int buf, int k0) {
#pragma unroll
        for (int i = 0; i < 32; ++i) {
            const int ri = w * 16 + (i >> 1);
            const int h  = i & 1;
            const int slot = h * 64 + lane;
            const int c = (slot & ~31) | ((slot & 31) ^ (ri & 31));
            long elem = (long)(row0 + ri) * IN_DIM + k0 + c;
            if (elem > maxElem) elem = maxElem;   // row/k tail clamp
            const float* gp = feat + elem;
            float* lp = &xs[buf][ri * KC2 + h * 64];   // wave-uniform base
            __builtin_amdgcn_global_load_lds(
                (const __attribute__((address_space(1))) void*)gp,
                (__attribute__((address_space(3))) void*)lp, 4, 0, 0);
        }
    };

#define COMPUTE2(buf, k0v, KMAX)                                            \
    {                                                                       \
        const float* xrow = &xs[buf][r * KC2];                              \
        _Pragma("unroll 8")                                                 \
        for (int kk = 0; kk < (KMAX); ++kk) {                               \
            const float x = xrow[(kk & ~31) | ((kk & 31) ^ rx)];            \
            const float4 wv = *(const float4*)(W1 +                         \
                (size_t)((k0v) + kk) * HID + wq * 4);                       \
            acc[0] += x * wv.x; acc[1] += x * wv.y;                         \
            acc[2] += x * wv.z; acc[3] += x * wv.w;                         \
        }                                                                   \
    }

    stage(0, 0);
    __syncthreads();   // tile 0 resident
    for (int it = 0; it < NT2 - 1; ++it) {
        stage((it & 1) ^ 1, (it + 1) * KC2);   // async prefetch next tile
        COMPUTE2(it & 1, it * KC2, KC2);       // compute current tile
        __syncthreads();                       // drain prefetch + buf reuse
    }
    COMPUTE2((NT2 - 1) & 1, (NT2 - 1) * KC2, KLAST2);
#undef COMPUTE2

    const int grow = row0 + r;
    if (grow < N)
        *(float4*)(xw1 + (size_t)grow * HID + wq * 4) =
            make_float4(acc[0], acc[1], acc[2], acc[3]);

    // ---- histogram chunk (overlaps other blocks' gemm memory stalls) ----
    const int e0 = blockIdx.x * EPB;
    const int e1 = min(e0 + EPB, E);
    for (int e = e0 + t; e < e1; e += 256)
        atomicAdd(&cnt[edst[e]], 1);
}

// ---------------- CSR build: scan -> counting-sort fill -----------------------
// block = 256 threads, 4 elems/thread -> 1024 per block
__global__ __launch_bounds__(256) void scan1_kernel(
    const int* __restrict__ cnt, int* __restrict__ offs,
    int* __restrict__ bsum, int N)
{
    __shared__ int lds[256];
    const int t = threadIdx.x, b = blockIdx.x;
    const int base = b * 1024 + t * 4;
    int c0 = 0, c1 = 0, c2 = 0, c3 = 0;
    if (base + 0 < N) c0 = cnt[base + 0];
    if (base + 1 < N) c1 = cnt[base + 1];
    if (base + 2 < N) c2 = cnt[base + 2];
    if (base + 3 < N) c3 = cnt[base + 3];
    const int s = c0 + c1 + c2 + c3;
    lds[t] = s;
    __syncthreads();
    for (int off = 1; off < 256; off <<= 1) {
        int v = (t >= off) ? lds[t - off] : 0;
        __syncthreads();
        lds[t] += v;
        __syncthreads();
    }
    const int excl = lds[t] - s;
    if (t == 255) bsum[b] = lds[255];
    int run = excl;
    if (base + 0 < N) { offs[base + 0] = run; run += c0; }
    if (base + 1 < N) { offs[base + 1] = run; run += c1; }
    if (base + 2 < N) { offs[base + 2] = run; run += c2; }
    if (base + 3 < N) { offs[base + 3] = run; run += c3; }
}

// single block: exclusive scan of up to 256 block sums
__global__ __launch_bounds__(256) void scan2_kernel(
    const int* __restrict__ bsum, int* __restrict__ bbase, int NB)
{
    __shared__ int lds[256];
    const int t = threadIdx.x;
    const int v = (t < NB) ? bsum[t] : 0;
    lds[t] = v;
    __syncthreads();
    for (int off = 1; off < 256; off <<= 1) {
        int u = (t >= off) ? lds[t - off] : 0;
        __syncthreads();
        lds[t] += u;
        __syncthreads();
    }
    bbase[t] = lds[t] - v;
}

__global__ __launch_bounds__(256) void scan3_kernel(
    int* __restrict__ offs, int* __restrict__ cursor,
    const int* __restrict__ bbase, int N, int E)
{
    const int t = threadIdx.x, b = blockIdx.x;
    const int add = bbase[b];
    const int base = b * 1024 + t * 4;
#pragma unroll
    for (int i = 0; i < 4; ++i) {
        const int idx = base + i;
        if (idx < N) {
            const int v = offs[idx] + add;
            offs[idx] = v;
            cursor[idx] = v;
        }
    }
    if (b == 0 && t == 0) offs[N] = E;
}

__global__ __launch_bounds__(256) void fill_kernel(
    const int* __restrict__ src, const int* __restrict__ dst,
    const float* __restrict__ a, int* __restrict__ cursor,
    uint2* __restrict__ pairs, int E)
{
    const int e = blockIdx.x * 256 + threadIdx.x;
    if (e >= E) return;
    const int d = dst[e];
    const int pos = atomicAdd(&cursor[d], 1);
    pairs[pos] = make_uint2((unsigned)src[e], __float_as_uint(a[e]));
}

// ------- gather1: agg = sum(a*xw1[src]) ; fused h=relu(agg+b1); xw2 = h@W2 ----
// one wave per dst row: 16 lanes (dims) x 4 edge groups
__global__ __launch_bounds__(256) void gather1_kernel(
    const uint2* __restrict__ pairs, const int* __restrict__ offs,
    const float* __restrict__ xw1, const float* __restrict__ b1,
    const float* __restrict__ W2, float* __restrict__ xw2, int N)
{
    __shared__ float w2s[HID * OUTD];
    const int t = threadIdx.x;
    if (t < HID * OUTD) w2s[t] = W2[t];
    __syncthreads();
    const int lane = t & 63;
    const int r = blockIdx.x * 4 + (t >> 6);
    if (r >= N) return;
    const int dim = lane & 15;
    const int grp = lane >> 4;
    const int start = offs[r], end = offs[r + 1];
    float acc0 = 0.f, acc1 = 0.f;
    int e = start + grp;
    for (; e + 4 < end; e += 8) {
        const uint2 p0 = pairs[e];
        const uint2 p1 = pairs[e + 4];
        acc0 += __uint_as_float(p0.y) * xw1[(long)p0.x * HID + dim];
        acc1 += __uint_as_float(p1.y) * xw1[(long)p1.x * HID + dim];
    }
    if (e < end) {
        const uint2 p0 = pairs[e];
        acc0 += __uint_as_float(p0.y) * xw1[(long)p0.x * HID + dim];
    }
    float acc = acc0 + acc1;
    acc += __shfl_xor(acc, 16);
    acc += __shfl_xor(acc, 32);
    const float h = fmaxf(acc + b1[dim], 0.f);
    float sacc = 0.f;
    const int c = (dim < OUTD) ? dim : 0;
#pragma unroll
    for (int j = 0; j < HID; ++j) {
        const float hj = __shfl(h, j);
        sacc += hj * w2s[j * OUTD + c];
    }
    if (lane < 8) xw2[(long)r * 8 + lane] = (lane < OUTD) ? sacc : 0.f;
}

// ------- gather2: o = sum(a*xw2[src]) + b2 ; fused log_softmax -> out ---------
__global__ __launch_bounds__(256) void gather2_kernel(
    const uint2* __restrict__ pairs, const int* __restrict__ offs,
    const float* __restrict__ xw2, const float* __restrict__ b2,
    float* __restrict__ out, int N)
{
    const int t = threadIdx.x;
    const int lane = t & 63;
    const int r = blockIdx.x * 4 + (t >> 6);
    if (r >= N) return;
    const int dim = lane & 7;
    const int grp = lane >> 3;
    const int start = offs[r], end = offs[r + 1];
    float acc0 = 0.f, acc1 = 0.f;
    int e = start + grp;
    for (; e + 8 < end; e += 16) {
        const uint2 p0 = pairs[e];
        const uint2 p1 = pairs[e + 8];
        acc0 += __uint_as_float(p0.y) * xw2[(long)p0.x * 8 + dim];
        acc1 += __uint_as_float(p1.y) * xw2[(long)p1.x * 8 + dim];
    }
    if (e < end) {
        const uint2 p0 = pairs[e];
        acc0 += __uint_as_float(p0.y) * xw2[(long)p0.x * 8 + dim];
    }
    float acc = acc0 + acc1;
    acc += __shfl_xor(acc, 8);
    acc += __shfl_xor(acc, 16);
    acc += __shfl_xor(acc, 32);
    float x = (dim < OUTD) ? (acc + b2[dim]) : -FLT_MAX;
    float m = x;
    m = fmaxf(m, __shfl_xor(m, 1));
    m = fmaxf(m, __shfl_xor(m, 2));
    m = fmaxf(m, __shfl_xor(m, 4));
    const float ev = (dim < OUTD) ? expf(x - m) : 0.f;
    float ssum = ev;
    ssum += __shfl_xor(ssum, 1);
    ssum += __shfl_xor(ssum, 2);
    ssum += __shfl_xor(ssum, 4);
    const float lg = logf(ssum);
    if (lane < OUTD) out[(long)r * OUTD + lane] = x - m - lg;
}

extern "C" void kernel_launch(void* const* d_in, const int* in_sizes, int n_in,
                              void* d_out, int out_size, void* d_ws, size_t ws_size,
                              hipStream_t stream)
{
    const float* feat  = (const float*)d_in[0];
    const int*   esrc  = (const int*)d_in[1];
    const int*   edst  = (const int*)d_in[2];
    const float* avals = (const float*)d_in[3];
    const float* W1    = (const float*)d_in[4];
    const float* b1    = (const float*)d_in[5];
    const float* W2    = (const float*)d_in[6];
    const float* b2    = (const float*)d_in[7];
    float* out = (float*)d_out;

    const int N = in_sizes[0] / IN_DIM;   // 150000
    const int E = in_sizes[1];            // 4800000
    const int NB = (N + 1023) / 1024;     // 147 (<=256 for scan2)

    // workspace layout
    char* p = (char*)d_ws;
    float* xw1   = (float*)p; p += (size_t)N * HID * sizeof(float);
    float* xw2   = (float*)p; p += (size_t)N * 8 * sizeof(float);
    int*   cnt   = (int*)p;   p += (size_t)N * sizeof(int);
    int*   offs  = (int*)p;   p += (size_t)(N + 1) * sizeof(int);
    int*   cursor= (int*)p;   p += (size_t)N * sizeof(int);
    int*   bsum  = (int*)p;   p += 256 * sizeof(int);
    int*   bbase = (int*)p;   p += 256 * sizeof(int);
    p = (char*)(((uintptr_t)p + 15) & ~(uintptr_t)15);
    uint2* pairs = (uint2*)p;

    hipMemsetAsync(cnt, 0, (size_t)N * sizeof(int), stream);

    const int G = (N + BR - 1) / BR;        // 2344 blocks
    const int EPB = (E + G - 1) / G;        // 2048 edges per block
    gemm1_hist_kernel<<<G, 256, 0, stream>>>(feat, W1, xw1, N, edst, cnt, E, EPB);

    scan1_kernel<<<NB, 256, 0, stream>>>(cnt, offs, bsum, N);
    scan2_kernel<<<1, 256, 0, stream>>>(bsum, bbase, NB);
    scan3_kernel<<<NB, 256, 0, stream>>>(offs, cursor, bbase, N, E);
    fill_kernel<<<(E + 255) / 256, 256, 0, stream>>>(esrc, edst, avals, cursor, pairs, E);

    gather1_kernel<<<(N + 3) / 4, 256, 0, stream>>>(pairs, offs, xw1, b1, W2, xw2, N);
    gather2_kernel<<<(N + 3) / 4, 256, 0, stream>>>(pairs, offs, xw2, b2, out, N);
}

// Round 5
// 1079.161 us; speedup vs baseline: 1.3343x; 1.3343x over previous
//
#include <hip/hip_runtime.h>
#include <float.h>
#include <stdint.h>

#define IN_DIM 1433
#define HID 16
#define OUTD 7

#define KC 32
#define GROWS 128
#define NT ((IN_DIM + KC - 1) / KC)      // 45 tiles
#define KLAST (IN_DIM - (NT - 1) * KC)   // 25

// ---------------- GEMM1: xw1[N][16] = feat[N][1433] @ W1[1433][16] -------------
// 256 threads = 4 waves. 128 rows/block, 2 threads per row (8 dims each).
// Double-buffered LDS tile xs[2][128][32] staged via WIDTH-16 global_load_lds:
// one instruction = 64 lanes x 16B = 8 rows x 128B (1 cache line per row).
// Bank-conflict fix (rule #21, both-sides): physical 16B-slot p of row r holds
// logical col-block p^(r&7) (pre-swizzled GLOBAL source, linear LDS dest);
// read side fetches logical block s at physical slot s^(r&7) via ds_read_b128
// -> lanes r=0..7 hit 8 disjoint bank-quads = all 32 banks, conflict-free.
__global__ __launch_bounds__(256, 4) void gemm1_kernel(
    const float* __restrict__ feat, const float* __restrict__ W1,
    float* __restrict__ xw1, int N)
{
    __shared__ float xs[2][GROWS * KC];   // 2 * 16 KB
    const int t = threadIdx.x;
    const int lane = t & 63;
    const int w = t >> 6;                 // wave 0..3
    const int row0 = blockIdx.x * GROWS;
    const long maxBase = (long)N * IN_DIM - 4;   // keep 16B reads in-bounds

    const int r   = t & (GROWS - 1);   // row owned for compute (0..127)
    const int rx8 = r & 7;
    const int jh  = t >> 7;            // 0: dims 0-7, 1: dims 8-15
    const int jhu = __builtin_amdgcn_readfirstlane(jh);
    const float* __restrict__ wptr = W1 + jhu * 8;

    float acc[8];
#pragma unroll
    for (int j = 0; j < 8; ++j) acc[j] = 0.f;

    const int lrow = lane >> 3;   // 0..7: row within the instruction's 8-row group
    const int lp   = lane & 7;    // 16B slot 0..7 within the row

    // stage one 128x32 tile: 4 width-16 DMA instrs per wave (32 rows/wave)
    auto stage = [&](int buf, int k0) {
#pragma unroll
        for (int i = 0; i < 4; ++i) {
            const int ri = w * 32 + i * 8 + lrow;     // row in tile
            const int cs = ((lp ^ (ri & 7)) << 2);    // swizzled col (floats)
            long base = (long)(row0 + ri) * IN_DIM + k0 + cs;
            if (base > maxBase) base = maxBase;       // row/k tail clamp
            const float* gp = feat + base;
            float* lpd = &xs[buf][(w * 32 + i * 8) * KC];  // wave-uniform base
            __builtin_amdgcn_global_load_lds(
                (const __attribute__((address_space(1))) void*)gp,
                (__attribute__((address_space(3))) void*)lpd, 16, 0, 0);
        }
    };

#define COMPUTE(buf, k0v, KMAX)                                               \
    {                                                                         \
        const float* xrow = &xs[buf][r * KC];                                 \
        _Pragma("unroll")                                                     \
        for (int s8 = 0; s8 < ((KMAX) + 3) / 4; ++s8) {                       \
            const float4 xv = *(const float4*)&xrow[((s8 ^ rx8) << 2)];       \
            const float xarr[4] = {xv.x, xv.y, xv.z, xv.w};                   \
            _Pragma("unroll")                                                 \
            for (int j = 0; j < 4; ++j) {                                     \
                const int kk = s8 * 4 + j;                                    \
                if (kk < (KMAX)) {                                            \
                    const float x = xarr[j];                                  \
                    const float* wk = wptr + (size_t)((k0v) + kk) * HID;      \
                    const float4 wa = *(const float4*)(wk);                   \
                    const float4 wb = *(const float4*)(wk + 4);               \
                    acc[0] += x * wa.x; acc[1] += x * wa.y;                   \
                    acc[2] += x * wa.z; acc[3] += x * wa.w;                   \
                    acc[4] += x * wb.x; acc[5] += x * wb.y;                   \
                    acc[6] += x * wb.z; acc[7] += x * wb.w;                   \
                }                                                             \
            }                                                                 \
        }                                                                     \
    }

    stage(0, 0);
    __syncthreads();   // drains vmcnt -> tile 0 resident
    for (int it = 0; it < NT - 1; ++it) {
        stage((it & 1) ^ 1, (it + 1) * KC);   // async prefetch next tile
        COMPUTE(it & 1, it * KC, KC);         // compute current tile
        __syncthreads();                      // drain prefetch + protect reuse
    }
    COMPUTE((NT - 1) & 1, (NT - 1) * KC, KLAST);
#undef COMPUTE

    const int grow = row0 + r;
    if (grow < N) {
        float4* o = (float4*)(xw1 + (size_t)grow * HID + jh * 8);
        o[0] = make_float4(acc[0], acc[1], acc[2], acc[3]);
        o[1] = make_float4(acc[4], acc[5], acc[6], acc[7]);
    }
}

// ---------------- CSR build: histogram -> scan -> counting-sort fill ----------
__global__ __launch_bounds__(256) void hist_kernel(
    const int* __restrict__ dst, int* __restrict__ cnt, int E)
{
    const int e = blockIdx.x * 256 + threadIdx.x;
    if (e < E) atomicAdd(&cnt[dst[e]], 1);
}

// block = 256 threads, 4 elems/thread -> 1024 per block
__global__ __launch_bounds__(256) void scan1_kernel(
    const int* __restrict__ cnt, int* __restrict__ offs,
    int* __restrict__ bsum, int N)
{
    __shared__ int lds[256];
    const int t = threadIdx.x, b = blockIdx.x;
    const int base = b * 1024 + t * 4;
    int c0 = 0, c1 = 0, c2 = 0, c3 = 0;
    if (base + 0 < N) c0 = cnt[base + 0];
    if (base + 1 < N) c1 = cnt[base + 1];
    if (base + 2 < N) c2 = cnt[base + 2];
    if (base + 3 < N) c3 = cnt[base + 3];
    const int s = c0 + c1 + c2 + c3;
    lds[t] = s;
    __syncthreads();
    for (int off = 1; off < 256; off <<= 1) {
        int v = (t >= off) ? lds[t - off] : 0;
        __syncthreads();
        lds[t] += v;
        __syncthreads();
    }
    const int excl = lds[t] - s;
    if (t == 255) bsum[b] = lds[255];
    int run = excl;
    if (base + 0 < N) { offs[base + 0] = run; run += c0; }
    if (base + 1 < N) { offs[base + 1] = run; run += c1; }
    if (base + 2 < N) { offs[base + 2] = run; run += c2; }
    if (base + 3 < N) { offs[base + 3] = run; run += c3; }
}

// single block: exclusive scan of up to 256 block sums
__global__ __launch_bounds__(256) void scan2_kernel(
    const int* __restrict__ bsum, int* __restrict__ bbase, int NB)
{
    __shared__ int lds[256];
    const int t = threadIdx.x;
    const int v = (t < NB) ? bsum[t] : 0;
    lds[t] = v;
    __syncthreads();
    for (int off = 1; off < 256; off <<= 1) {
        int u = (t >= off) ? lds[t - off] : 0;
        __syncthreads();
        lds[t] += u;
        __syncthreads();
    }
    bbase[t] = lds[t] - v;
}

__global__ __launch_bounds__(256) void scan3_kernel(
    int* __restrict__ offs, int* __restrict__ cursor,
    const int* __restrict__ bbase, int N, int E)
{
    const int t = threadIdx.x, b = blockIdx.x;
    const int add = bbase[b];
    const int base = b * 1024 + t * 4;
#pragma unroll
    for (int i = 0; i < 4; ++i) {
        const int idx = base + i;
        if (idx < N) {
            const int v = offs[idx] + add;
            offs[idx] = v;
            cursor[idx] = v;
        }
    }
    if (b == 0 && t == 0) offs[N] = E;
}

__global__ __launch_bounds__(256) void fill_kernel(
    const int* __restrict__ src, const int* __restrict__ dst,
    const float* __restrict__ a, int* __restrict__ cursor,
    uint2* __restrict__ pairs, int E)
{
    const int e = blockIdx.x * 256 + threadIdx.x;
    if (e >= E) return;
    const int d = dst[e];
    const int pos = atomicAdd(&cursor[d], 1);
    pairs[pos] = make_uint2((unsigned)src[e], __float_as_uint(a[e]));
}

// ------- gather1: agg = sum(a*xw1[src]) ; fused h=relu(agg+b1); xw2 = h@W2 ----
// one wave per dst row: 16 lanes (dims) x 4 edge groups
__global__ __launch_bounds__(256) void gather1_kernel(
    const uint2* __restrict__ pairs, const int* __restrict__ offs,
    const float* __restrict__ xw1, const float* __restrict__ b1,
    const float* __restrict__ W2, float* __restrict__ xw2, int N)
{
    __shared__ float w2s[HID * OUTD];
    const int t = threadIdx.x;
    if (t < HID * OUTD) w2s[t] = W2[t];
    __syncthreads();
    const int lane = t & 63;
    const int r = blockIdx.x * 4 + (t >> 6);
    if (r >= N) return;
    const int dim = lane & 15;
    const int grp = lane >> 4;
    const int start = offs[r], end = offs[r + 1];
    float acc0 = 0.f, acc1 = 0.f;
    int e = start + grp;
    for (; e + 4 < end; e += 8) {
        const uint2 p0 = pairs[e];
        const uint2 p1 = pairs[e + 4];
        acc0 += __uint_as_float(p0.y) * xw1[(long)p0.x * HID + dim];
        acc1 += __uint_as_float(p1.y) * xw1[(long)p1.x * HID + dim];
    }
    if (e < end) {
        const uint2 p0 = pairs[e];
        acc0 += __uint_as_float(p0.y) * xw1[(long)p0.x * HID + dim];
    }
    float acc = acc0 + acc1;
    acc += __shfl_xor(acc, 16);
    acc += __shfl_xor(acc, 32);
    const float h = fmaxf(acc + b1[dim], 0.f);
    float sacc = 0.f;
    const int c = (dim < OUTD) ? dim : 0;
#pragma unroll
    for (int j = 0; j < HID; ++j) {
        const float hj = __shfl(h, j);
        sacc += hj * w2s[j * OUTD + c];
    }
    if (lane < 8) xw2[(long)r * 8 + lane] = (lane < OUTD) ? sacc : 0.f;
}

// ------- gather2: o = sum(a*xw2[src]) + b2 ; fused log_softmax -> out ---------
__global__ __launch_bounds__(256) void gather2_kernel(
    const uint2* __restrict__ pairs, const int* __restrict__ offs,
    const float* __restrict__ xw2, const float* __restrict__ b2,
    float* __restrict__ out, int N)
{
    const int t = threadIdx.x;
    const int lane = t & 63;
    const int r = blockIdx.x * 4 + (t >> 6);
    if (r >= N) return;
    const int dim = lane & 7;
    const int grp = lane >> 3;
    const int start = offs[r], end = offs[r + 1];
    float acc0 = 0.f, acc1 = 0.f;
    int e = start + grp;
    for (; e + 8 < end; e += 16) {
        const uint2 p0 = pairs[e];
        const uint2 p1 = pairs[e + 8];
        acc0 += __uint_as_float(p0.y) * xw2[(long)p0.x * 8 + dim];
        acc1 += __uint_as_float(p1.y) * xw2[(long)p1.x * 8 + dim];
    }
    if (e < end) {
        const uint2 p0 = pairs[e];
        acc0 += __uint_as_float(p0.y) * xw2[(long)p0.x * 8 + dim];
    }
    float acc = acc0 + acc1;
    acc += __shfl_xor(acc, 8);
    acc += __shfl_xor(acc, 16);
    acc += __shfl_xor(acc, 32);
    float x = (dim < OUTD) ? (acc + b2[dim]) : -FLT_MAX;
    float m = x;
    m = fmaxf(m, __shfl_xor(m, 1));
    m = fmaxf(m, __shfl_xor(m, 2));
    m = fmaxf(m, __shfl_xor(m, 4));
    const float ev = (dim < OUTD) ? expf(x - m) : 0.f;
    float ssum = ev;
    ssum += __shfl_xor(ssum, 1);
    ssum += __shfl_xor(ssum, 2);
    ssum += __shfl_xor(ssum, 4);
    const float lg = logf(ssum);
    if (lane < OUTD) out[(long)r * OUTD + lane] = x - m - lg;
}

extern "C" void kernel_launch(void* const* d_in, const int* in_sizes, int n_in,
                              void* d_out, int out_size, void* d_ws, size_t ws_size,
                              hipStream_t stream)
{
    const float* feat  = (const float*)d_in[0];
    const int*   esrc  = (const int*)d_in[1];
    const int*   edst  = (const int*)d_in[2];
    const float* avals = (const float*)d_in[3];
    const float* W1    = (const float*)d_in[4];
    const float* b1    = (const float*)d_in[5];
    const float* W2    = (const float*)d_in[6];
    const float* b2    = (const float*)d_in[7];
    float* out = (float*)d_out;

    const int N = in_sizes[0] / IN_DIM;   // 150000
    const int E = in_sizes[1];            // 4800000
    const int NB = (N + 1023) / 1024;     // 147 (<=256 for scan2)

    // workspace layout
    char* p = (char*)d_ws;
    float* xw1   = (float*)p; p += (size_t)N * HID * sizeof(float);
    float* xw2   = (float*)p; p += (size_t)N * 8 * sizeof(float);
    int*   cnt   = (int*)p;   p += (size_t)N * sizeof(int);
    int*   offs  = (int*)p;   p += (size_t)(N + 1) * sizeof(int);
    int*   cursor= (int*)p;   p += (size_t)N * sizeof(int);
    int*   bsum  = (int*)p;   p += 256 * sizeof(int);
    int*   bbase = (int*)p;   p += 256 * sizeof(int);
    p = (char*)(((uintptr_t)p + 15) & ~(uintptr_t)15);
    uint2* pairs = (uint2*)p;

    hipMemsetAsync(cnt, 0, (size_t)N * sizeof(int), stream);

    gemm1_kernel<<<(N + GROWS - 1) / GROWS, 256, 0, stream>>>(feat, W1, xw1, N);

    hist_kernel<<<(E + 255) / 256, 256, 0, stream>>>(edst, cnt, E);
    scan1_kernel<<<NB, 256, 0, stream>>>(cnt, offs, bsum, N);
    scan2_kernel<<<1, 256, 0, stream>>>(bsum, bbase, NB);
    scan3_kernel<<<NB, 256, 0, stream>>>(offs, cursor, bbase, N, E);
    fill_kernel<<<(E + 255) / 256, 256, 0, stream>>>(esrc, edst, avals, cursor, pairs, E);

    gather1_kernel<<<(N + 3) / 4, 256, 0, stream>>>(pairs, offs, xw1, b1, W2, xw2, N);
    gather2_kernel<<<(N + 3) / 4, 256, 0, stream>>>(pairs, offs, xw2, b2, out, N);
}